// Round 18
// baseline (71.245 us; speedup 1.0000x reference)
//
#include <hip/hip_runtime.h>

#define NB 512
#define SLOTS 32
#define D 1024
#define D4 256           // D/4 (float4 per row)
#define TC 8             // tokens per chunk (per part)
#define CAP 64           // list capacity per bucket
#define TAU_INV 10.0f
#define BT 512           // threads per block (8 waves)

// ---- kernel 0: zero the per-bucket counters ----
__global__ void k_zero(int* __restrict__ cnt) {
    if (threadIdx.x < NB) cnt[threadIdx.x] = 0;
}

// ---- kernel 1: build per-bucket token lists (order nondeterministic, but
//      per-token math is order-invariant → deterministic output) ----
__global__ void k_build(const int* __restrict__ tids, int n,
                        int* __restrict__ cnt, int* __restrict__ list) {
    int i = blockIdx.x * 256 + threadIdx.x;
    if (i < n) {
        int b = tids[i] & (NB - 1);
        int p = atomicAdd(&cnt[b], 1);
        if (p < CAP) list[b * CAP + p] = i;
    }
}

// ---- kernel A: unified queries, token-parallel, barrier-free.
//      wave per token; result STAGED IN d_out (overwritten by the final
//      value pass for the same token — in-block read-before-write order).
__global__ __launch_bounds__(256, 2)
void k_uq(const float* __restrict__ query,    // [NT][D]
          const int*   __restrict__ tids,     // [NT]
          const float* __restrict__ centroid, // [NB][D]
          float*       __restrict__ uq_out,   // [NT][D] (= d_out)
          int n_tokens)
{
    const int lane = threadIdx.x & 63;
    const int wid  = threadIdx.x >> 6;       // 0..3
    const int tok  = blockIdx.x * 4 + wid;
    if (tok >= n_tokens) return;

    const int b = tids[tok] & (NB - 1);
    const float4* q4 = (const float4*)(query + (size_t)tok * D);
    const float4* cb = (const float4*)(centroid + (size_t)b * D);

    float4 qv[4], anc[4];
    float ss = 0.f;
    #pragma unroll
    for (int j = 0; j < 4; ++j) {
        qv[j]  = q4[lane + 64 * j];
        anc[j] = cb[lane + 64 * j];
        ss += qv[j].x*qv[j].x + qv[j].y*qv[j].y + qv[j].z*qv[j].z + qv[j].w*qv[j].w;
    }
    #pragma unroll
    for (int off = 32; off >= 1; off >>= 1) ss += __shfl_xor(ss, off);
    const float qn = 0.5f / fmaxf(sqrtf(ss), 1e-12f);   // folds ALPHA=0.5
    float4 uv[4];
    float ss2 = 0.f;
    #pragma unroll
    for (int j = 0; j < 4; ++j) {
        uv[j].x = qv[j].x * qn + 0.5f * anc[j].x;
        uv[j].y = qv[j].y * qn + 0.5f * anc[j].y;
        uv[j].z = qv[j].z * qn + 0.5f * anc[j].z;
        uv[j].w = qv[j].w * qn + 0.5f * anc[j].w;
        ss2 += uv[j].x*uv[j].x + uv[j].y*uv[j].y + uv[j].z*uv[j].z + uv[j].w*uv[j].w;
    }
    #pragma unroll
    for (int off = 32; off >= 1; off >>= 1) ss2 += __shfl_xor(ss2, off);
    const float un = 1.0f / fmaxf(sqrtf(ss2), 1e-12f);
    float4* o4 = (float4*)(uq_out + (size_t)tok * D);
    #pragma unroll
    for (int j = 0; j < 4; ++j)
        o4[lane + 64 * j] = make_float4(uv[j].x*un, uv[j].y*un, uv[j].z*un, uv[j].w*un);
}

// ---- kernel B: slim main (no query phase), 8 WAVES per block.
//      grid = 2*NB (2-way parity split, traffic ~133 MB unchanged);
//      4 blocks/CU x 8 waves = 32 waves/CU static if VGPR<=64 (R17's slim
//      body measured exactly 64). Single-round phases:
//      score = wave w owns slots [4w,4w+4); softmax = wave w owns token w;
//      value = column-group g (tidx>>8) owns tokens [4g,4g+4).
//      uq aliases out: each token's uq row is read strictly before its out
//      row is written (in-block barrier order).
__global__ __launch_bounds__(BT, 2)
void k_main(const int*   __restrict__ tids,     // [NT]
            const float*              uq,       // [NT][D] (= d_out)
            const float* __restrict__ skeys,    // [NB*SLOTS][D]
            const float* __restrict__ svals,    // [NB*SLOTS][D]
            const int*   __restrict__ stids,    // [NB*SLOTS]
            float*                    out,      // [NT][D]
            const int*   __restrict__ cnt,
            const int*   __restrict__ list)
{
    const int bucket = blockIdx.x & (NB - 1);   // parts share XCD (512%8==0)
    const int part   = blockIdx.x >> 9;         // 0/1
    const int tidx   = threadIdx.x;             // 0..511
    const int lane   = tidx & 63;
    const int wid    = tidx >> 6;               // 0..7

    const int count = min(cnt[bucket], CAP);
    const int ncnt  = (count - part + 1) >> 1;  // tokens owned by this part
    if (ncnt <= 0) return;

    __shared__ float s_scores[TC][SLOTS];       // 1 KB
    __shared__ float s_probs[TC][SLOTS];        // 1 KB
    __shared__ int   s_tok[TC];
    __shared__ int   s_ttid[TC];

    const int slot_tid = stids[bucket * SLOTS + (lane & 31)];
    const float4* kb = (const float4*)(skeys + (size_t)bucket * SLOTS * D);
    const float4* vb = (const float4*)(svals + (size_t)bucket * SLOTS * D);

    for (int c0 = 0; c0 < ncnt; c0 += TC) {
        const int nt = min(TC, ncnt - c0);

        // ---- preamble: token ids for this chunk ----
        if (tidx < nt) {
            const int tok = list[bucket * CAP + part + 2 * (c0 + tidx)];
            s_tok[tidx]  = tok;
            s_ttid[tidx] = tids[tok];
        }
        __syncthreads();   // barrier 1: s_tok visible

        // ---- scores: ONE round; wave w owns slots [4w, 4w+4) ----
        {
            const int sbase = wid * 4;
            const float4* kr = kb + (size_t)sbase * D4;
            float4 k0[4], k1[4], k2[4], k3[4];
            #pragma unroll
            for (int j = 0; j < 4; ++j) {
                k0[j] = kr[0 * D4 + lane + 64 * j];
                k1[j] = kr[1 * D4 + lane + 64 * j];
                k2[j] = kr[2 * D4 + lane + 64 * j];
                k3[j] = kr[3 * D4 + lane + 64 * j];
            }
            for (int t = 0; t < nt; ++t) {          // runtime bound: anti-spill
                const float4* u4 = (const float4*)(uq + (size_t)s_tok[t] * D);
                float P0 = 0.f, P1 = 0.f, P2 = 0.f, P3 = 0.f;
                #pragma unroll
                for (int j = 0; j < 4; ++j) {
                    float4 u = u4[lane + 64 * j];   // global, L1-broadcast
                    P0 += k0[j].x*u.x + k0[j].y*u.y + k0[j].z*u.z + k0[j].w*u.w;
                    P1 += k1[j].x*u.x + k1[j].y*u.y + k1[j].z*u.z + k1[j].w*u.w;
                    P2 += k2[j].x*u.x + k2[j].y*u.y + k2[j].z*u.z + k2[j].w*u.w;
                    P3 += k3[j].x*u.x + k3[j].y*u.y + k3[j].z*u.z + k3[j].w*u.w;
                }
                // batched paired-halving reduce: 4 values, 7 shfl (R10-verified)
                {
                    const bool hi = (lane & 1) != 0;
                    const float sA = hi ? P0 : P2, kA = hi ? P2 : P0;
                    P0 = kA + __shfl_xor(sA, 1);
                    const float sB = hi ? P1 : P3, kB = hi ? P3 : P1;
                    P1 = kB + __shfl_xor(sB, 1);
                }
                {
                    const bool hi = (lane & 2) != 0;
                    const float sA = hi ? P0 : P1, kA = hi ? P1 : P0;
                    P0 = kA + __shfl_xor(sA, 2);
                }
                P0 += __shfl_xor(P0, 4);
                P0 += __shfl_xor(P0, 8);
                P0 += __shfl_xor(P0, 16);
                P0 += __shfl_xor(P0, 32);
                // lane l<4 holds slot id = ((l&1)<<1)|((l>>1)&1)
                if (lane < 4)
                    s_scores[t][sbase + (((lane & 1) << 1) | ((lane >> 1) & 1))] = P0;
            }
        }
        __syncthreads();   // barrier 2: s_scores visible

        // ---- softmax + hard-match: wave w owns token w; lanes 0..31 ----
        if (wid < nt && lane < 32) {
            const float sc = s_scores[wid][lane];
            float mx = sc;
            #pragma unroll
            for (int off = 16; off >= 1; off >>= 1) mx = fmaxf(mx, __shfl_xor(mx, off));
            const float e = __expf((sc - mx) * TAU_INV);
            const float f = (slot_tid == s_ttid[wid]) ? 1.f : 0.f;
            float es = e, ms = f;
            #pragma unroll
            for (int off = 16; off >= 1; off >>= 1) {
                es += __shfl_xor(es, off);
                ms += __shfl_xor(ms, off);
            }
            s_probs[wid][lane] = (ms > 0.f) ? f / (ms + 1e-9f) : e / es;
        }
        __syncthreads();   // barrier 3: s_probs visible

        // ---- values: col = tidx&255; grp = tidx>>8 owns tokens [4g,4g+4).
        //      Both grps stream all 32 rows (2nd grp hits L1/L2); acc[4]. ----
        {
            const int col = tidx & 255;
            const int grp = tidx >> 8;
            float4 acc[4];
            #pragma unroll
            for (int k = 0; k < 4; ++k) acc[k] = make_float4(0.f, 0.f, 0.f, 0.f);

            #pragma unroll 1
            for (int s0 = 0; s0 < SLOTS; s0 += 8) {
                float4 v[8];
                #pragma unroll
                for (int i = 0; i < 8; ++i) v[i] = vb[(s0 + i) * D4 + col];
                #pragma unroll
                for (int k = 0; k < 4; ++k) {
                    const int t = grp * 4 + k;
                    if (t < nt) {
                        const float4 pA = ((const float4*)s_probs[t])[(s0 >> 2) + 0];
                        const float4 pB = ((const float4*)s_probs[t])[(s0 >> 2) + 1];
                        acc[k].x += pA.x*v[0].x + pA.y*v[1].x + pA.z*v[2].x + pA.w*v[3].x
                                  + pB.x*v[4].x + pB.y*v[5].x + pB.z*v[6].x + pB.w*v[7].x;
                        acc[k].y += pA.x*v[0].y + pA.y*v[1].y + pA.z*v[2].y + pA.w*v[3].y
                                  + pB.x*v[4].y + pB.y*v[5].y + pB.z*v[6].y + pB.w*v[7].y;
                        acc[k].z += pA.x*v[0].z + pA.y*v[1].z + pA.z*v[2].z + pA.w*v[3].z
                                  + pB.x*v[4].z + pB.y*v[5].z + pB.z*v[6].z + pB.w*v[7].z;
                        acc[k].w += pA.x*v[0].w + pA.y*v[1].w + pA.z*v[2].w + pA.w*v[3].w
                                  + pB.x*v[4].w + pB.y*v[5].w + pB.z*v[6].w + pB.w*v[7].w;
                    }
                }
            }
            #pragma unroll
            for (int k = 0; k < 4; ++k) {
                const int t = grp * 4 + k;
                if (t < nt) {
                    ((float4*)(out + (size_t)s_tok[t] * D))[col] = acc[k];
                }
            }
        }
        if (c0 + TC < ncnt) __syncthreads();   // only multi-chunk blocks
    }
}

extern "C" void kernel_launch(void* const* d_in, const int* in_sizes, int n_in,
                              void* d_out, int out_size, void* d_ws, size_t ws_size,
                              hipStream_t stream) {
    const float* query    = (const float*)d_in[0];
    const int*   tids     = (const int*)  d_in[1];
    const float* skeys    = (const float*)d_in[2];
    const float* svals    = (const float*)d_in[3];
    const int*   stids    = (const int*)  d_in[4];
    const float* centroid = (const float*)d_in[5];
    float* out = (float*)d_out;
    const int n_tokens = in_sizes[1];

    int* cnt  = (int*)d_ws;             // [NB]
    int* list = cnt + NB;               // [NB*CAP]

    k_zero<<<1, 512, 0, stream>>>(cnt);
    k_build<<<(n_tokens + 255) / 256, 256, 0, stream>>>(tids, n_tokens, cnt, list);
    k_uq<<<(n_tokens + 3) / 4, 256, 0, stream>>>(query, tids, centroid, out, n_tokens);
    k_main<<<NB * 2, BT, 0, stream>>>(tids, out, skeys, svals, stids,
                                      out, cnt, list);
}

// Round 19
// 56.285 us; speedup vs baseline: 1.2658x; 1.2658x over previous
//
#include <hip/hip_runtime.h>

#define NB 512
#define SLOTS 32
#define D 1024
#define D4 256           // D/4 (float4 per row)
#define TC 8             // tokens per chunk (per part)
#define CAP 64           // list capacity per bucket
#define TAU_INV 10.0f
#define BT 256           // threads per block (4 waves)

// ---- kernel 0: zero the per-bucket counters ----
__global__ void k_zero(int* __restrict__ cnt) {
    if (threadIdx.x < NB) cnt[threadIdx.x] = 0;
}

// ---- kernel 1: build per-bucket token lists (order nondeterministic, but
//      per-token math is order-invariant → deterministic output) ----
__global__ void k_build(const int* __restrict__ tids, int n,
                        int* __restrict__ cnt, int* __restrict__ list) {
    int i = blockIdx.x * 256 + threadIdx.x;
    if (i < n) {
        int b = tids[i] & (NB - 1);
        int p = atomicAdd(&cnt[b], 1);
        if (p < CAP) list[b * CAP + p] = i;
    }
}

// ---- kernel 2: EXACT R11 (best, 55.6us) + score-phase software pipelining:
//      the t-loop's 4 LDS uq loads are double-buffered in registers so the
//      ~120cy LDS latency hides under the 7-shfl reduce of the previous t.
//      (R16 ablation: score phase dominates; its stall is the dependent
//      load->FMA->reduce chain repeated nt*2 times with latency exposed.)
__global__ __launch_bounds__(BT, 2)
void k_main(const float* __restrict__ query,    // [NT][D]
            const int*   __restrict__ tids,     // [NT]
            const float* __restrict__ skeys,    // [NB*SLOTS][D]
            const float* __restrict__ svals,    // [NB*SLOTS][D]
            const int*   __restrict__ stids,    // [NB*SLOTS]
            const float* __restrict__ centroid, // [NB][D]
            float*       __restrict__ out,      // [NT][D]
            const int*   __restrict__ cnt,
            const int*   __restrict__ list)
{
    const int bucket = blockIdx.x & (NB - 1);   // parts share XCD (512%8==0)
    const int part   = blockIdx.x >> 9;         // 0/1
    const int tidx   = threadIdx.x;             // 0..255
    const int lane   = tidx & 63;
    const int wid    = tidx >> 6;               // 0..3

    const int count = min(cnt[bucket], CAP);
    const int ncnt  = (count - part + 1) >> 1;  // tokens owned by this part
    if (ncnt <= 0) return;

    __shared__ float s_uq[TC][D];               // 32 KB
    __shared__ float s_scores[TC][SLOTS];       // 1 KB
    __shared__ float s_probs[TC][SLOTS];        // 1 KB
    __shared__ int   s_tok[TC];
    __shared__ int   s_ttid[TC];

    const int slot_tid = stids[bucket * SLOTS + (lane & 31)];
    const float4* kb = (const float4*)(skeys + (size_t)bucket * SLOTS * D);
    const float4* vb = (const float4*)(svals + (size_t)bucket * SLOTS * D);
    const float4* cb = (const float4*)(centroid + (size_t)bucket * D);

    for (int c0 = 0; c0 < ncnt; c0 += TC) {
        const int nt = min(TC, ncnt - c0);

        // ---- query phase: wave w owns tokens w, w+4 (anchor from L2) ----
        for (int t = wid; t < nt; t += 4) {
            const int tok = list[bucket * CAP + part + 2 * (c0 + t)];
            const float4* q4 = (const float4*)(query + (size_t)tok * D);
            float4 qv[4], anc[4];
            float ss = 0.f;
            #pragma unroll
            for (int j = 0; j < 4; ++j) {
                qv[j]  = q4[lane + 64 * j];
                anc[j] = cb[lane + 64 * j];
                ss += qv[j].x*qv[j].x + qv[j].y*qv[j].y + qv[j].z*qv[j].z + qv[j].w*qv[j].w;
            }
            #pragma unroll
            for (int off = 32; off >= 1; off >>= 1) ss += __shfl_xor(ss, off);
            const float qn = 0.5f / fmaxf(sqrtf(ss), 1e-12f);   // folds ALPHA=0.5
            float4 uv[4];
            float ss2 = 0.f;
            #pragma unroll
            for (int j = 0; j < 4; ++j) {
                uv[j].x = qv[j].x * qn + 0.5f * anc[j].x;
                uv[j].y = qv[j].y * qn + 0.5f * anc[j].y;
                uv[j].z = qv[j].z * qn + 0.5f * anc[j].z;
                uv[j].w = qv[j].w * qn + 0.5f * anc[j].w;
                ss2 += uv[j].x*uv[j].x + uv[j].y*uv[j].y + uv[j].z*uv[j].z + uv[j].w*uv[j].w;
            }
            #pragma unroll
            for (int off = 32; off >= 1; off >>= 1) ss2 += __shfl_xor(ss2, off);
            const float un = 1.0f / fmaxf(sqrtf(ss2), 1e-12f);
            #pragma unroll
            for (int j = 0; j < 4; ++j) {
                ((float4*)s_uq[t])[lane + 64 * j] =
                    make_float4(uv[j].x*un, uv[j].y*un, uv[j].z*un, uv[j].w*un);
            }
            if (lane == 0) { s_tok[t] = tok; s_ttid[t] = tids[tok]; }
        }
        __syncthreads();

        // ---- scores: 2 rounds; wave owns 4 slots/round; uq double-buffered ----
        #pragma unroll 1
        for (int rnd = 0; rnd < 2; ++rnd) {
            const int sbase = rnd * 16 + wid * 4;
            const float4* kr = kb + (size_t)sbase * D4;
            float4 k0[4], k1[4], k2[4], k3[4];
            #pragma unroll
            for (int j = 0; j < 4; ++j) {
                k0[j] = kr[0 * D4 + lane + 64 * j];
                k1[j] = kr[1 * D4 + lane + 64 * j];
                k2[j] = kr[2 * D4 + lane + 64 * j];
                k3[j] = kr[3 * D4 + lane + 64 * j];
            }
            float4 uc[4];
            #pragma unroll
            for (int j = 0; j < 4; ++j) uc[j] = ((const float4*)s_uq[0])[lane + 64 * j];
            for (int t = 0; t < nt; ++t) {          // runtime bound: anti-spill
                // prefetch next token's uq while this one reduces
                float4 un4[4];
                const int tn = (t + 1 < nt) ? t + 1 : t;
                #pragma unroll
                for (int j = 0; j < 4; ++j) un4[j] = ((const float4*)s_uq[tn])[lane + 64 * j];

                float P0 = 0.f, P1 = 0.f, P2 = 0.f, P3 = 0.f;
                #pragma unroll
                for (int j = 0; j < 4; ++j) {
                    const float4 u = uc[j];
                    P0 += k0[j].x*u.x + k0[j].y*u.y + k0[j].z*u.z + k0[j].w*u.w;
                    P1 += k1[j].x*u.x + k1[j].y*u.y + k1[j].z*u.z + k1[j].w*u.w;
                    P2 += k2[j].x*u.x + k2[j].y*u.y + k2[j].z*u.z + k2[j].w*u.w;
                    P3 += k3[j].x*u.x + k3[j].y*u.y + k3[j].z*u.z + k3[j].w*u.w;
                }
                // batched paired-halving reduce: 4 values, 7 shfl (R10-verified)
                {
                    const bool hi = (lane & 1) != 0;
                    const float sA = hi ? P0 : P2, kA = hi ? P2 : P0;
                    P0 = kA + __shfl_xor(sA, 1);
                    const float sB = hi ? P1 : P3, kB = hi ? P3 : P1;
                    P1 = kB + __shfl_xor(sB, 1);
                }
                {
                    const bool hi = (lane & 2) != 0;
                    const float sA = hi ? P0 : P1, kA = hi ? P1 : P0;
                    P0 = kA + __shfl_xor(sA, 2);
                }
                P0 += __shfl_xor(P0, 4);
                P0 += __shfl_xor(P0, 8);
                P0 += __shfl_xor(P0, 16);
                P0 += __shfl_xor(P0, 32);
                // lane l<4 holds slot id = ((l&1)<<1)|((l>>1)&1)
                if (lane < 4)
                    s_scores[t][sbase + (((lane & 1) << 1) | ((lane >> 1) & 1))] = P0;
                #pragma unroll
                for (int j = 0; j < 4; ++j) uc[j] = un4[j];
            }
        }
        __syncthreads();

        // ---- softmax + hard-match: wave w owns tokens w, w+4; lanes 0..31 ----
        for (int t = wid; t < nt; t += 4) {
            if (lane < 32) {
                const float sc = s_scores[t][lane];
                float mx = sc;
                #pragma unroll
                for (int off = 16; off >= 1; off >>= 1) mx = fmaxf(mx, __shfl_xor(mx, off));
                const float e = __expf((sc - mx) * TAU_INV);
                const float f = (slot_tid == s_ttid[t]) ? 1.f : 0.f;
                float es = e, ms = f;
                #pragma unroll
                for (int off = 16; off >= 1; off >>= 1) {
                    es += __shfl_xor(es, off);
                    ms += __shfl_xor(ms, off);
                }
                s_probs[t][lane] = (ms > 0.f) ? f / (ms + 1e-9f) : e / es;
            }
        }
        __syncthreads();

        // ---- values: thread owns float4 column tidx; 4 rounds of 8 rows ----
        {
            float4 acc[TC];
            #pragma unroll
            for (int t = 0; t < TC; ++t) acc[t] = make_float4(0.f, 0.f, 0.f, 0.f);

            #pragma unroll 1
            for (int s0 = 0; s0 < SLOTS; s0 += 8) {
                float4 v[8];
                #pragma unroll
                for (int i = 0; i < 8; ++i) v[i] = vb[(s0 + i) * D4 + tidx];
                #pragma unroll
                for (int t = 0; t < TC; ++t) {
                    if (t < nt) {
                        const float4 pA = ((const float4*)s_probs[t])[(s0 >> 2) + 0];
                        const float4 pB = ((const float4*)s_probs[t])[(s0 >> 2) + 1];
                        acc[t].x += pA.x*v[0].x + pA.y*v[1].x + pA.z*v[2].x + pA.w*v[3].x
                                  + pB.x*v[4].x + pB.y*v[5].x + pB.z*v[6].x + pB.w*v[7].x;
                        acc[t].y += pA.x*v[0].y + pA.y*v[1].y + pA.z*v[2].y + pA.w*v[3].y
                                  + pB.x*v[4].y + pB.y*v[5].y + pB.z*v[6].y + pB.w*v[7].y;
                        acc[t].z += pA.x*v[0].z + pA.y*v[1].z + pA.z*v[2].z + pA.w*v[3].z
                                  + pB.x*v[4].z + pB.y*v[5].z + pB.z*v[6].z + pB.w*v[7].z;
                        acc[t].w += pA.x*v[0].w + pA.y*v[1].w + pA.z*v[2].w + pA.w*v[3].w
                                  + pB.x*v[4].w + pB.y*v[5].w + pB.z*v[6].w + pB.w*v[7].w;
                    }
                }
            }
            #pragma unroll
            for (int t = 0; t < TC; ++t) {
                if (t < nt) {
                    ((float4*)(out + (size_t)s_tok[t] * D))[tidx] = acc[t];
                }
            }
        }
        __syncthreads();   // next chunk rewrites s_uq/s_tok
    }
}

extern "C" void kernel_launch(void* const* d_in, const int* in_sizes, int n_in,
                              void* d_out, int out_size, void* d_ws, size_t ws_size,
                              hipStream_t stream) {
    const float* query    = (const float*)d_in[0];
    const int*   tids     = (const int*)  d_in[1];
    const float* skeys    = (const float*)d_in[2];
    const float* svals    = (const float*)d_in[3];
    const int*   stids    = (const int*)  d_in[4];
    const float* centroid = (const float*)d_in[5];
    float* out = (float*)d_out;
    const int n_tokens = in_sizes[1];

    int* cnt  = (int*)d_ws;             // [NB]
    int* list = cnt + NB;               // [NB*CAP]

    k_zero<<<1, 512, 0, stream>>>(cnt);
    k_build<<<(n_tokens + 255) / 256, 256, 0, stream>>>(tids, n_tokens, cnt, list);
    k_main<<<NB * 2, BT, 0, stream>>>(query, tids, skeys, svals, stids,
                                      centroid, out, cnt, list);
}